// Round 8
// baseline (80.565 us; speedup 1.0000x reference)
//
#include <hip/hip_runtime.h>
#include <hip/hip_fp16.h>
#include <math.h>

#define EPSF 1e-15f
#define MAX_TANH_F (1.0f - 1e-5f)
#define KDIM 512
#define NOUT 256
#define BM 32
#define BK 64

typedef __attribute__((ext_vector_type(8))) __bf16 bf16x8;
typedef __attribute__((ext_vector_type(4))) float f32x4;

__device__ __forceinline__ float artanh_clip(float x) {
    x = fminf(fmaxf(x, -MAX_TANH_F), MAX_TANH_F);
    return atanhf(x);
}

__device__ __forceinline__ void unpack2h(unsigned int u, float& a, float& b) {
    __half2 h = __builtin_bit_cast(__half2, u);
    a = __low2float(h);
    b = __high2float(h);
}

__device__ __forceinline__ bf16x8 cvt8(const float4& a, const float4& b) {
    bf16x8 r;
    r[0] = (__bf16)a.x; r[1] = (__bf16)a.y; r[2] = (__bf16)a.z; r[3] = (__bf16)a.w;
    r[4] = (__bf16)b.x; r[5] = (__bf16)b.y; r[6] = (__bf16)b.z; r[7] = (__bf16)b.w;
    return r;
}
__device__ __forceinline__ float sq8(const float4& a, const float4& b) {
    return a.x*a.x + a.y*a.y + a.z*a.z + a.w*a.w
         + b.x*b.x + b.y*b.y + b.z*b.z + b.w*b.w;
}

// P2: Wp[s][nt][lane][8] bf16 B-fragment layout (col=nt*16+(lane&15), k=s*32+(lane>>4)*8+j)
__global__ __launch_bounds__(64) void prep_w_kernel(
    const float* __restrict__ W, unsigned int* __restrict__ Wp)
{
    const int b = blockIdx.x;       // b = s*16 + nt, 256 blocks
    const int l = threadIdx.x;      // 64 lanes
    const int k0 = (b >> 4) * 32 + (l >> 4) * 8;
    const int col = (b & 15) * 16 + (l & 15);
    bf16x8 v;
    #pragma unroll
    for (int j = 0; j < 8; ++j) v[j] = (__bf16)W[(size_t)(k0 + j) * NOUT + col];
    *(uint4*)(Wp + ((size_t)b * 64 + l) * 4) = __builtin_bit_cast(uint4, v);
}

// K1: fused stage+GEMM+mobius_matvec. Block = 32 rows x 256 cols, 8 waves;
// wave = 32 rows x 32 cols (2 col-tiles, 8 MFMA/kk). A: global->reg (2-kk
// lookahead) -> LDS dbuf (XOR swizzle, conflict-free); B: reg rolling s+2.
__global__ __launch_bounds__(512, 4) void gemm_mobius_kernel(
    const float* __restrict__ feat, const uint4* __restrict__ Wp,
    __half* __restrict__ h, float* __restrict__ hnorm2,
    float scale, int N)
{
    __shared__ float lds_a[2][BM * BK];   // 16 KB
    __shared__ float sred[8][BM];
    __shared__ float sfac[BM];
    __shared__ float sxn2[BM];

    const int tid  = threadIdx.x;
    const int wave = tid >> 6;            // 0..7
    const int lane = tid & 63;
    const int rr   = lane & 15;
    const int g    = lane >> 4;
    const int base = blockIdx.x * BM;

    // staging map: thread -> row srow = tid>>4 (0..31), float4-slot sslot = tid&15
    const int srow  = tid >> 4;
    const int sslot = tid & 15;
    const int grow = base + srow;
    const float* gsrc = feat + (size_t)(grow < N ? grow : N - 1) * KDIM + sslot * 4;
    const int woff = srow * BK + ((sslot ^ (srow & 15)) << 2);

    f32x4 acc[2][2];
    #pragma unroll
    for (int hh = 0; hh < 2; ++hh)
        #pragma unroll
        for (int t = 0; t < 2; ++t) acc[hh][t] = (f32x4){0.f, 0.f, 0.f, 0.f};

    const uint4* wp = Wp + lane;
    const int tb = 2 * wave;              // this wave's first col-tile

    // B prologue: s = 0,1
    uint4 Bs[2][2];
    #pragma unroll
    for (int p = 0; p < 2; ++p)
        #pragma unroll
        for (int t = 0; t < 2; ++t)
            Bs[p][t] = wp[(size_t)(p * 16 + tb + t) * 64];

    // A prologue: stage kk=0, prefetch kk=1
    float4 nav[2];
    {
        float4 v = *(const float4*)(gsrc);
        nav[1] = *(const float4*)(gsrc + BK);
        *(float4*)&lds_a[0][woff] = v;
    }
    __syncthreads();

    float xs0 = 0.f, xs1 = 0.f;

    #pragma unroll
    for (int kk = 0; kk < 8; ++kk) {
        if (kk + 2 < 8) nav[kk & 1] = *(const float4*)(gsrc + (kk + 2) * BK);
        const float* buf = lds_a[kk & 1];
        #pragma unroll
        for (int ss = 0; ss < 2; ++ss) {
            const int s = kk * 2 + ss;
            const int ls0 = ((ss * 8 + g * 2)     ^ rr) << 2;
            const int ls1 = ((ss * 8 + g * 2 + 1) ^ rr) << 2;
            float4 a00 = *(const float4*)(buf + rr * BK + ls0);
            float4 a01 = *(const float4*)(buf + rr * BK + ls1);
            float4 a10 = *(const float4*)(buf + (16 + rr) * BK + ls0);
            float4 a11 = *(const float4*)(buf + (16 + rr) * BK + ls1);
            xs0 += sq8(a00, a01);
            xs1 += sq8(a10, a11);
            bf16x8 ah0 = cvt8(a00, a01);
            bf16x8 ah1 = cvt8(a10, a11);
            uint4 b0 = Bs[s & 1][0], b1 = Bs[s & 1][1];
            if (s + 2 < 16) {
                Bs[s & 1][0] = wp[(size_t)((s + 2) * 16 + tb) * 64];
                Bs[s & 1][1] = wp[(size_t)((s + 2) * 16 + tb + 1) * 64];
            }
            acc[0][0] = __builtin_amdgcn_mfma_f32_16x16x32_bf16(ah0, __builtin_bit_cast(bf16x8, b0), acc[0][0], 0, 0, 0);
            acc[1][0] = __builtin_amdgcn_mfma_f32_16x16x32_bf16(ah1, __builtin_bit_cast(bf16x8, b0), acc[1][0], 0, 0, 0);
            acc[0][1] = __builtin_amdgcn_mfma_f32_16x16x32_bf16(ah0, __builtin_bit_cast(bf16x8, b1), acc[0][1], 0, 0, 0);
            acc[1][1] = __builtin_amdgcn_mfma_f32_16x16x32_bf16(ah1, __builtin_bit_cast(bf16x8, b1), acc[1][1], 0, 0, 0);
        }
        if (kk + 1 < 8) *(float4*)&lds_a[(kk + 1) & 1][woff] = nav[(kk + 1) & 1];
        __syncthreads();
    }

    // xn2 (raw, unscaled): identical in every wave; wave 0 publishes
    xs0 += __shfl_xor(xs0, 16); xs0 += __shfl_xor(xs0, 32);
    xs1 += __shfl_xor(xs1, 16); xs1 += __shfl_xor(xs1, 32);
    if (wave == 0 && lane < 16) { sxn2[lane] = xs0; sxn2[16 + lane] = xs1; }

    // per-wave partial ||mx_raw||^2 over this wave's 32 cols, per row
    #pragma unroll
    for (int hh = 0; hh < 2; ++hh) {
        #pragma unroll
        for (int r = 0; r < 4; ++r) {
            float p = acc[hh][0][r] * acc[hh][0][r] + acc[hh][1][r] * acc[hh][1][r];
            p += __shfl_xor(p, 1);
            p += __shfl_xor(p, 2);
            p += __shfl_xor(p, 4);
            p += __shfl_xor(p, 8);
            if (rr == 0) sred[wave][hh * 16 + g * 4 + r] = p;
        }
    }
    __syncthreads();

    if (tid < BM) {
        const int r = tid;
        float mx2 = 0.f;
        #pragma unroll
        for (int w = 0; w < 8; ++w) mx2 += sred[w][r];
        const float mxn = fmaxf(scale * sqrtf(mx2), EPSF);
        const float xn  = fmaxf(scale * sqrtf(sxn2[r]), EPSF);
        float ttv = tanhf(mxn / xn * artanh_clip(xn));
        float fc  = ttv * scale / mxn;
        if (mxn <= 1e-10f) { fc = 0.f; ttv = 0.f; }
        sfac[r] = fc;
        if (base + r < N) hnorm2[base + r] = ttv * ttv;
    }
    __syncthreads();

    #pragma unroll
    for (int hh = 0; hh < 2; ++hh) {
        #pragma unroll
        for (int r = 0; r < 4; ++r) {
            const int row_r = base + hh * 16 + g * 4 + r;
            if (row_r < N) {
                const float fc = sfac[hh * 16 + g * 4 + r];
                __half* hr = h + (size_t)row_r * NOUT + wave * 32 + rr;
                hr[0]  = __float2half(acc[hh][0][r] * fc);
                hr[16] = __float2half(acc[hh][1][r] * fc);
            }
        }
    }
}

// K2: sequential mobius scan. 16 lanes per row, 4 rows/wave; depth-4 gather
// prefetch; y2 via one load + shuffle broadcast; v_rcp for per-step divide.
__global__ __launch_bounds__(256) void aggregate_kernel(
    const __half* __restrict__ h, const float* __restrict__ hnorm2,
    const int* __restrict__ src, const float* __restrict__ bias,
    float* __restrict__ out, float scale, int N)
{
    const int wave = threadIdx.x >> 6;
    const int lane = threadIdx.x & 63;
    const int n0 = (blockIdx.x * 4 + wave) * 4;   // first of this wave's 4 rows
    if (n0 >= N) return;
    const int g = lane >> 4;      // row slot
    const int q = lane & 15;      // component group
    const int myrow = n0 + g;
    const bool rowok = myrow < N;

    size_t smax = (size_t)N * 16 - 1;
    size_t soff = (size_t)n0 * 16 + lane;
    int sidx = src[soff <= smax ? soff : smax];
    float y2v = hnorm2[sidx];

    int idx[16];
    float y2[16];
    #pragma unroll
    for (int j = 0; j < 16; ++j) {
        idx[j] = __shfl(sidx, (lane & 48) + j);
        y2[j]  = __shfl(y2v, (lane & 48) + j);
    }

    // c init from j=0; prefetch j=1..4 into slots 0..3
    uint4 cur0, cur1;
    {
        const uint4* hp = (const uint4*)(h + (size_t)idx[0] * NOUT);
        cur0 = hp[q * 2]; cur1 = hp[q * 2 + 1];
    }
    uint4 pa[4], pb[4];
    #pragma unroll
    for (int p = 0; p < 4; ++p) {
        const uint4* hp = (const uint4*)(h + (size_t)idx[p + 1] * NOUT);
        pa[p] = hp[q * 2]; pb[p] = hp[q * 2 + 1];
    }

    float c[16];
    unpack2h(cur0.x, c[0], c[1]);   unpack2h(cur0.y, c[2], c[3]);
    unpack2h(cur0.z, c[4], c[5]);   unpack2h(cur0.w, c[6], c[7]);
    unpack2h(cur1.x, c[8], c[9]);   unpack2h(cur1.y, c[10], c[11]);
    unpack2h(cur1.z, c[12], c[13]); unpack2h(cur1.w, c[14], c[15]);
    float c2 = y2[0];

    #pragma unroll
    for (int j = 1; j < 16; ++j) {
        const int slot = (j - 1) & 3;
        uint4 p0 = pa[slot], p1 = pb[slot];
        if (j + 4 < 16) {
            const uint4* hp = (const uint4*)(h + (size_t)idx[j + 4] * NOUT);
            pa[slot] = hp[q * 2]; pb[slot] = hp[q * 2 + 1];
        }
        float yv[16];
        unpack2h(p0.x, yv[0], yv[1]);   unpack2h(p0.y, yv[2], yv[3]);
        unpack2h(p0.z, yv[4], yv[5]);   unpack2h(p0.w, yv[6], yv[7]);
        unpack2h(p1.x, yv[8], yv[9]);   unpack2h(p1.y, yv[10], yv[11]);
        unpack2h(p1.z, yv[12], yv[13]); unpack2h(p1.w, yv[14], yv[15]);

        float xp = 0.f;
        #pragma unroll
        for (int i = 0; i < 16; ++i) xp = fmaf(c[i], yv[i], xp);
        xp += __shfl_xor(xp, 1);
        xp += __shfl_xor(xp, 2);
        xp += __shfl_xor(xp, 4);
        xp += __shfl_xor(xp, 8);
        const float xy = xp;

        const float A = 1.f + 2.f * xy + y2[j];
        const float B = 1.f - c2;
        const float den = fmaxf(1.f + 2.f * xy + c2 * y2[j], EPSF);
        const float inv = __builtin_amdgcn_rcpf(den);
        #pragma unroll
        for (int i = 0; i < 16; ++i) c[i] = (fmaf(A, c[i], B * yv[i])) * inv;
        c2 = fmaxf((A * A * c2 + 2.f * A * B * xy + B * B * y2[j]) * (inv * inv), 0.f);
    }

    // rst *= scale
    #pragma unroll
    for (int i = 0; i < 16; ++i) c[i] *= scale;
    c2 *= scale * scale;

    // mobius_add(rst, bias)
    float bv[16];
    {
        const float4* bp = (const float4*)(bias + q * 16);
        float4 b0 = bp[0], b1 = bp[1], b2 = bp[2], b3 = bp[3];
        bv[0]=b0.x; bv[1]=b0.y; bv[2]=b0.z; bv[3]=b0.w;
        bv[4]=b1.x; bv[5]=b1.y; bv[6]=b1.z; bv[7]=b1.w;
        bv[8]=b2.x; bv[9]=b2.y; bv[10]=b2.z; bv[11]=b2.w;
        bv[12]=b3.x; bv[13]=b3.y; bv[14]=b3.z; bv[15]=b3.w;
    }
    float bp_ = 0.f, xp_ = 0.f;
    #pragma unroll
    for (int i = 0; i < 16; ++i) { bp_ = fmaf(bv[i], bv[i], bp_); xp_ = fmaf(c[i], bv[i], xp_); }
    bp_ += __shfl_xor(bp_, 1); xp_ += __shfl_xor(xp_, 1);
    bp_ += __shfl_xor(bp_, 2); xp_ += __shfl_xor(xp_, 2);
    bp_ += __shfl_xor(bp_, 4); xp_ += __shfl_xor(xp_, 4);
    bp_ += __shfl_xor(bp_, 8); xp_ += __shfl_xor(xp_, 8);
    const float bb = bp_, xy = xp_;

    const float A = 1.f + 2.f * xy + bb;
    const float B = 1.f - c2;
    const float den = fmaxf(1.f + 2.f * xy + c2 * bb, EPSF);
    const float inv = 1.f / den;
    float r4[16];
    #pragma unroll
    for (int i = 0; i < 16; ++i) r4[i] = fmaf(A, c[i], B * bv[i]) * inv;
    const float rn2 = fmaxf((A * A * c2 + 2.f * A * B * xy + B * B * bb) * (inv * inv), 0.f);

    // expmap0(relu(logmap0(.)))
    const float rn = fmaxf(sqrtf(rn2), EPSF);
    const float lf = artanh_clip(rn) / rn;
    float u[16];
    float up = 0.f;
    #pragma unroll
    for (int i = 0; i < 16; ++i) { u[i] = fmaxf(r4[i] * lf, 0.f); up = fmaf(u[i], u[i], up); }
    up += __shfl_xor(up, 1);
    up += __shfl_xor(up, 2);
    up += __shfl_xor(up, 4);
    up += __shfl_xor(up, 8);
    const float un = fmaxf(sqrtf(up), EPSF);
    const float ef = tanhf(un) / un;

    if (rowok) {
        float* op = out + (size_t)myrow * NOUT + q * 16;
        float4 o;
        o.x = u[0]*ef;  o.y = u[1]*ef;  o.z = u[2]*ef;  o.w = u[3]*ef;  ((float4*)op)[0] = o;
        o.x = u[4]*ef;  o.y = u[5]*ef;  o.z = u[6]*ef;  o.w = u[7]*ef;  ((float4*)op)[1] = o;
        o.x = u[8]*ef;  o.y = u[9]*ef;  o.z = u[10]*ef; o.w = u[11]*ef; ((float4*)op)[2] = o;
        o.x = u[12]*ef; o.y = u[13]*ef; o.z = u[14]*ef; o.w = u[15]*ef; ((float4*)op)[3] = o;
    }
}

extern "C" void kernel_launch(void* const* d_in, const int* in_sizes, int n_in,
                              void* d_out, int out_size, void* d_ws, size_t ws_size,
                              hipStream_t stream) {
    const float* feat   = (const float*)d_in[0];
    const float* weight = (const float*)d_in[1];
    const float* bias   = (const float*)d_in[2];
    const int*   src    = (const int*)d_in[3];

    const int OUT = in_sizes[2];            // 256
    const int IN  = in_sizes[1] / OUT;      // 512
    const int N   = in_sizes[0] / IN;       // 20000
    const int DEG = in_sizes[3] / N;        // 16
    (void)IN; (void)DEG; (void)out_size; (void)ws_size; (void)n_in;

    const float scale = 1.0f / sqrtf((float)DEG);

    // ws layout: h fp16 (N*256*2 B) | hnorm2 (N f32) | Wp (256 KB)
    char* ws = (char*)d_ws;
    __half* h     = (__half*)ws;
    float* hnorm2 = (float*)(ws + (size_t)N * NOUT * 2);
    unsigned int* Wp = (unsigned int*)(ws + (size_t)N * NOUT * 2 + (size_t)N * 4);

    float* out = (float*)d_out;

    const int nbm = (N + BM - 1) / BM;      // 625

    hipLaunchKernelGGL(prep_w_kernel, dim3(256), dim3(64), 0, stream,
                       weight, Wp);
    hipLaunchKernelGGL(gemm_mobius_kernel, dim3(nbm), dim3(512), 0, stream,
                       feat, (const uint4*)Wp, h, hnorm2, scale, N);
    hipLaunchKernelGGL(aggregate_kernel, dim3((N + 15) / 16), dim3(256), 0, stream,
                       h, hnorm2, src, bias, out, scale, N);
}

// Round 9
// 51.690 us; speedup vs baseline: 1.5586x; 1.5586x over previous
//
#include <hip/hip_runtime.h>
#include <hip/hip_fp16.h>
#include <math.h>

#define EPSF 1e-15f
#define MAX_TANH_F (1.0f - 1e-5f)
#define KDIM 512
#define NOUT 256
#define BM 32
#define BK 64

typedef __attribute__((ext_vector_type(8))) __bf16 bf16x8;
typedef __attribute__((ext_vector_type(4))) float f32x4;

__device__ __forceinline__ float artanh_clip(float x) {
    x = fminf(fmaxf(x, -MAX_TANH_F), MAX_TANH_F);
    return atanhf(x);
}

__device__ __forceinline__ void unpack2h(unsigned int u, float& a, float& b) {
    __half2 h = __builtin_bit_cast(__half2, u);
    a = __low2float(h);
    b = __high2float(h);
}

__device__ __forceinline__ bf16x8 cvt8(const float4& a, const float4& b) {
    bf16x8 r;
    r[0] = (__bf16)a.x; r[1] = (__bf16)a.y; r[2] = (__bf16)a.z; r[3] = (__bf16)a.w;
    r[4] = (__bf16)b.x; r[5] = (__bf16)b.y; r[6] = (__bf16)b.z; r[7] = (__bf16)b.w;
    return r;
}
__device__ __forceinline__ float sq8(const float4& a, const float4& b) {
    return a.x*a.x + a.y*a.y + a.z*a.z + a.w*a.w
         + b.x*b.x + b.y*b.y + b.z*b.z + b.w*b.w;
}

// P2: Wp[s][nt][lane][8] bf16 B-fragment layout (col=nt*16+(lane&15), k=s*32+(lane>>4)*8+j)
__global__ __launch_bounds__(64) void prep_w_kernel(
    const float* __restrict__ W, unsigned int* __restrict__ Wp)
{
    const int b = blockIdx.x;       // b = s*16 + nt, 256 blocks
    const int l = threadIdx.x;      // 64 lanes
    const int k0 = (b >> 4) * 32 + (l >> 4) * 8;
    const int col = (b & 15) * 16 + (l & 15);
    bf16x8 v;
    #pragma unroll
    for (int j = 0; j < 8; ++j) v[j] = (__bf16)W[(size_t)(k0 + j) * NOUT + col];
    *(uint4*)(Wp + ((size_t)b * 64 + l) * 4) = __builtin_bit_cast(uint4, v);
}

// K1 (R7-exact): fused stage+GEMM+mobius_matvec. Block = 32 rows x 256 cols,
// 4 waves; wave = 32 rows x 64 cols (16 MFMA/k-step). feat staged f32 -> LDS
// (dbuf, slot-XOR swizzle, conflict-free), bf16 cvt at LDS-read, exact f32
// row norms in-register, scale folded into epilogue.
__global__ __launch_bounds__(256) void gemm_mobius_kernel(
    const float* __restrict__ feat, const uint4* __restrict__ Wp,
    __half* __restrict__ h, float* __restrict__ hnorm2,
    float scale, int N)
{
    __shared__ float lds_a[2][BM * BK];   // 16 KB total
    __shared__ float sred[4][BM];
    __shared__ float sfac[BM];
    __shared__ float sxn2[BM];

    const int tid  = threadIdx.x;
    const int wave = tid >> 6;
    const int lane = tid & 63;
    const int rr   = lane & 15;
    const int g    = lane >> 4;
    const int base = blockIdx.x * BM;

    // staging map: thread t -> row srow = t>>3, floats sk..sk+7 of each BK slice
    const int srow = tid >> 3;
    const int sk   = (tid & 7) * 8;
    const int grow = base + srow;
    const float* gsrc = feat + (size_t)(grow < N ? grow : N - 1) * KDIM + sk;
    const int wslot0 = (((tid & 7) * 2)     ^ (srow & 15)) * 4;
    const int wslot1 = (((tid & 7) * 2 + 1) ^ (srow & 15)) * 4;

    f32x4 acc[2][4];
    #pragma unroll
    for (int hh = 0; hh < 2; ++hh)
        #pragma unroll
        for (int t = 0; t < 4; ++t) acc[hh][t] = (f32x4){0.f, 0.f, 0.f, 0.f};

    const uint4* wp = Wp + (size_t)wave * 4 * 64 + lane;

    // B prologue: s = 0,1
    uint4 B[2][4];
    #pragma unroll
    for (int p = 0; p < 2; ++p)
        #pragma unroll
        for (int t = 0; t < 4; ++t)
            B[p][t] = wp[((size_t)p * 16 + t) * 64];

    // stage kk = 0
    {
        float4 a = *(const float4*)(gsrc);
        float4 b = *(const float4*)(gsrc + 4);
        float* d = &lds_a[0][srow * BK];
        *(float4*)(d + wslot0) = a;
        *(float4*)(d + wslot1) = b;
    }
    __syncthreads();

    float xs0 = 0.f, xs1 = 0.f;
    float4 n0, n1;

    #pragma unroll
    for (int kk = 0; kk < 8; ++kk) {
        if (kk < 7) {
            n0 = *(const float4*)(gsrc + (kk + 1) * BK);
            n1 = *(const float4*)(gsrc + (kk + 1) * BK + 4);
        }
        const float* buf = lds_a[kk & 1];
        #pragma unroll
        for (int ss = 0; ss < 2; ++ss) {
            const int s = kk * 2 + ss;
            const int ls0 = ((ss * 8 + g * 2)     ^ rr) * 4;
            const int ls1 = ((ss * 8 + g * 2 + 1) ^ rr) * 4;
            float4 a00 = *(const float4*)(buf + rr * BK + ls0);
            float4 a01 = *(const float4*)(buf + rr * BK + ls1);
            float4 a10 = *(const float4*)(buf + (16 + rr) * BK + ls0);
            float4 a11 = *(const float4*)(buf + (16 + rr) * BK + ls1);
            xs0 += sq8(a00, a01);
            xs1 += sq8(a10, a11);
            bf16x8 ah0 = cvt8(a00, a01);
            bf16x8 ah1 = cvt8(a10, a11);
            uint4 b0 = B[s & 1][0], b1 = B[s & 1][1], b2 = B[s & 1][2], b3 = B[s & 1][3];
            if (s + 2 < 16) {
                #pragma unroll
                for (int t = 0; t < 4; ++t)
                    B[s & 1][t] = wp[((size_t)(s + 2) * 16 + t) * 64];
            }
            acc[0][0] = __builtin_amdgcn_mfma_f32_16x16x32_bf16(ah0, __builtin_bit_cast(bf16x8, b0), acc[0][0], 0, 0, 0);
            acc[1][0] = __builtin_amdgcn_mfma_f32_16x16x32_bf16(ah1, __builtin_bit_cast(bf16x8, b0), acc[1][0], 0, 0, 0);
            acc[0][1] = __builtin_amdgcn_mfma_f32_16x16x32_bf16(ah0, __builtin_bit_cast(bf16x8, b1), acc[0][1], 0, 0, 0);
            acc[1][1] = __builtin_amdgcn_mfma_f32_16x16x32_bf16(ah1, __builtin_bit_cast(bf16x8, b1), acc[1][1], 0, 0, 0);
            acc[0][2] = __builtin_amdgcn_mfma_f32_16x16x32_bf16(ah0, __builtin_bit_cast(bf16x8, b2), acc[0][2], 0, 0, 0);
            acc[1][2] = __builtin_amdgcn_mfma_f32_16x16x32_bf16(ah1, __builtin_bit_cast(bf16x8, b2), acc[1][2], 0, 0, 0);
            acc[0][3] = __builtin_amdgcn_mfma_f32_16x16x32_bf16(ah0, __builtin_bit_cast(bf16x8, b3), acc[0][3], 0, 0, 0);
            acc[1][3] = __builtin_amdgcn_mfma_f32_16x16x32_bf16(ah1, __builtin_bit_cast(bf16x8, b3), acc[1][3], 0, 0, 0);
        }
        if (kk < 7) {
            float* d = &lds_a[(kk + 1) & 1][srow * BK];
            *(float4*)(d + wslot0) = n0;
            *(float4*)(d + wslot1) = n1;
        }
        __syncthreads();
    }

    // xn2 (raw, unscaled): reduce across g-quarters; every wave identical, wave 0 publishes
    xs0 += __shfl_xor(xs0, 16); xs0 += __shfl_xor(xs0, 32);
    xs1 += __shfl_xor(xs1, 16); xs1 += __shfl_xor(xs1, 32);
    if (wave == 0 && lane < 16) { sxn2[lane] = xs0; sxn2[16 + lane] = xs1; }

    // per-wave partial ||mx_raw||^2 over this wave's 64 cols, per row
    #pragma unroll
    for (int hh = 0; hh < 2; ++hh) {
        #pragma unroll
        for (int r = 0; r < 4; ++r) {
            float p = 0.f;
            #pragma unroll
            for (int t = 0; t < 4; ++t) p += acc[hh][t][r] * acc[hh][t][r];
            p += __shfl_xor(p, 1);
            p += __shfl_xor(p, 2);
            p += __shfl_xor(p, 4);
            p += __shfl_xor(p, 8);
            if (rr == 0) sred[wave][hh * 16 + g * 4 + r] = p;
        }
    }
    __syncthreads();

    if (tid < BM) {
        const int r = tid;
        const float mx2 = sred[0][r] + sred[1][r] + sred[2][r] + sred[3][r];
        const float mxn = fmaxf(scale * sqrtf(mx2), EPSF);
        const float xn  = fmaxf(scale * sqrtf(sxn2[r]), EPSF);
        float ttv = tanhf(mxn / xn * artanh_clip(xn));
        float fc  = ttv * scale / mxn;     // applied to raw acc => scaled-mx direction
        if (mxn <= 1e-10f) { fc = 0.f; ttv = 0.f; }
        sfac[r] = fc;
        if (base + r < N) hnorm2[base + r] = ttv * ttv;
    }
    __syncthreads();

    #pragma unroll
    for (int hh = 0; hh < 2; ++hh) {
        #pragma unroll
        for (int r = 0; r < 4; ++r) {
            const int row_r = base + hh * 16 + g * 4 + r;
            if (row_r < N) {
                const float fc = sfac[hh * 16 + g * 4 + r];
                __half* hr = h + (size_t)row_r * NOUT + wave * 64 + rr;
                #pragma unroll
                for (int t = 0; t < 4; ++t) hr[t * 16] = __float2half(acc[hh][t][r] * fc);
            }
        }
    }
}

// K2: sequential mobius scan. 16 lanes per row, 4 rows/wave; depth-4 gather
// prefetch; y2 via one load + shuffle broadcast; v_rcp for per-step divide.
__global__ __launch_bounds__(256) void aggregate_kernel(
    const __half* __restrict__ h, const float* __restrict__ hnorm2,
    const int* __restrict__ src, const float* __restrict__ bias,
    float* __restrict__ out, float scale, int N)
{
    const int wave = threadIdx.x >> 6;
    const int lane = threadIdx.x & 63;
    const int n0 = (blockIdx.x * 4 + wave) * 4;   // first of this wave's 4 rows
    if (n0 >= N) return;
    const int g = lane >> 4;      // row slot
    const int q = lane & 15;      // component group
    const int myrow = n0 + g;
    const bool rowok = myrow < N;

    size_t smax = (size_t)N * 16 - 1;
    size_t soff = (size_t)n0 * 16 + lane;
    int sidx = src[soff <= smax ? soff : smax];
    float y2v = hnorm2[sidx];

    int idx[16];
    float y2[16];
    #pragma unroll
    for (int j = 0; j < 16; ++j) {
        idx[j] = __shfl(sidx, (lane & 48) + j);
        y2[j]  = __shfl(y2v, (lane & 48) + j);
    }

    // c init from j=0; prefetch j=1..4 into slots 0..3
    uint4 cur0, cur1;
    {
        const uint4* hp = (const uint4*)(h + (size_t)idx[0] * NOUT);
        cur0 = hp[q * 2]; cur1 = hp[q * 2 + 1];
    }
    uint4 pa[4], pb[4];
    #pragma unroll
    for (int p = 0; p < 4; ++p) {
        const uint4* hp = (const uint4*)(h + (size_t)idx[p + 1] * NOUT);
        pa[p] = hp[q * 2]; pb[p] = hp[q * 2 + 1];
    }

    float c[16];
    unpack2h(cur0.x, c[0], c[1]);   unpack2h(cur0.y, c[2], c[3]);
    unpack2h(cur0.z, c[4], c[5]);   unpack2h(cur0.w, c[6], c[7]);
    unpack2h(cur1.x, c[8], c[9]);   unpack2h(cur1.y, c[10], c[11]);
    unpack2h(cur1.z, c[12], c[13]); unpack2h(cur1.w, c[14], c[15]);
    float c2 = y2[0];

    #pragma unroll
    for (int j = 1; j < 16; ++j) {
        const int slot = (j - 1) & 3;
        uint4 p0 = pa[slot], p1 = pb[slot];
        if (j + 4 < 16) {
            const uint4* hp = (const uint4*)(h + (size_t)idx[j + 4] * NOUT);
            pa[slot] = hp[q * 2]; pb[slot] = hp[q * 2 + 1];
        }
        float yv[16];
        unpack2h(p0.x, yv[0], yv[1]);   unpack2h(p0.y, yv[2], yv[3]);
        unpack2h(p0.z, yv[4], yv[5]);   unpack2h(p0.w, yv[6], yv[7]);
        unpack2h(p1.x, yv[8], yv[9]);   unpack2h(p1.y, yv[10], yv[11]);
        unpack2h(p1.z, yv[12], yv[13]); unpack2h(p1.w, yv[14], yv[15]);

        float xp = 0.f;
        #pragma unroll
        for (int i = 0; i < 16; ++i) xp = fmaf(c[i], yv[i], xp);
        xp += __shfl_xor(xp, 1);
        xp += __shfl_xor(xp, 2);
        xp += __shfl_xor(xp, 4);
        xp += __shfl_xor(xp, 8);
        const float xy = xp;

        const float A = 1.f + 2.f * xy + y2[j];
        const float B = 1.f - c2;
        const float den = fmaxf(1.f + 2.f * xy + c2 * y2[j], EPSF);
        const float inv = __builtin_amdgcn_rcpf(den);
        #pragma unroll
        for (int i = 0; i < 16; ++i) c[i] = (fmaf(A, c[i], B * yv[i])) * inv;
        c2 = fmaxf((A * A * c2 + 2.f * A * B * xy + B * B * y2[j]) * (inv * inv), 0.f);
    }

    // rst *= scale
    #pragma unroll
    for (int i = 0; i < 16; ++i) c[i] *= scale;
    c2 *= scale * scale;

    // mobius_add(rst, bias)
    float bv[16];
    {
        const float4* bp = (const float4*)(bias + q * 16);
        float4 b0 = bp[0], b1 = bp[1], b2 = bp[2], b3 = bp[3];
        bv[0]=b0.x; bv[1]=b0.y; bv[2]=b0.z; bv[3]=b0.w;
        bv[4]=b1.x; bv[5]=b1.y; bv[6]=b1.z; bv[7]=b1.w;
        bv[8]=b2.x; bv[9]=b2.y; bv[10]=b2.z; bv[11]=b2.w;
        bv[12]=b3.x; bv[13]=b3.y; bv[14]=b3.z; bv[15]=b3.w;
    }
    float bp_ = 0.f, xp_ = 0.f;
    #pragma unroll
    for (int i = 0; i < 16; ++i) { bp_ = fmaf(bv[i], bv[i], bp_); xp_ = fmaf(c[i], bv[i], xp_); }
    bp_ += __shfl_xor(bp_, 1); xp_ += __shfl_xor(xp_, 1);
    bp_ += __shfl_xor(bp_, 2); xp_ += __shfl_xor(xp_, 2);
    bp_ += __shfl_xor(bp_, 4); xp_ += __shfl_xor(xp_, 4);
    bp_ += __shfl_xor(bp_, 8); xp_ += __shfl_xor(xp_, 8);
    const float bb = bp_, xy = xp_;

    const float A = 1.f + 2.f * xy + bb;
    const float B = 1.f - c2;
    const float den = fmaxf(1.f + 2.f * xy + c2 * bb, EPSF);
    const float inv = 1.f / den;
    float r4[16];
    #pragma unroll
    for (int i = 0; i < 16; ++i) r4[i] = fmaf(A, c[i], B * bv[i]) * inv;
    const float rn2 = fmaxf((A * A * c2 + 2.f * A * B * xy + B * B * bb) * (inv * inv), 0.f);

    // expmap0(relu(logmap0(.)))
    const float rn = fmaxf(sqrtf(rn2), EPSF);
    const float lf = artanh_clip(rn) / rn;
    float u[16];
    float up = 0.f;
    #pragma unroll
    for (int i = 0; i < 16; ++i) { u[i] = fmaxf(r4[i] * lf, 0.f); up = fmaf(u[i], u[i], up); }
    up += __shfl_xor(up, 1);
    up += __shfl_xor(up, 2);
    up += __shfl_xor(up, 4);
    up += __shfl_xor(up, 8);
    const float un = fmaxf(sqrtf(up), EPSF);
    const float ef = tanhf(un) / un;

    if (rowok) {
        float* op = out + (size_t)myrow * NOUT + q * 16;
        float4 o;
        o.x = u[0]*ef;  o.y = u[1]*ef;  o.z = u[2]*ef;  o.w = u[3]*ef;  ((float4*)op)[0] = o;
        o.x = u[4]*ef;  o.y = u[5]*ef;  o.z = u[6]*ef;  o.w = u[7]*ef;  ((float4*)op)[1] = o;
        o.x = u[8]*ef;  o.y = u[9]*ef;  o.z = u[10]*ef; o.w = u[11]*ef; ((float4*)op)[2] = o;
        o.x = u[12]*ef; o.y = u[13]*ef; o.z = u[14]*ef; o.w = u[15]*ef; ((float4*)op)[3] = o;
    }
}

extern "C" void kernel_launch(void* const* d_in, const int* in_sizes, int n_in,
                              void* d_out, int out_size, void* d_ws, size_t ws_size,
                              hipStream_t stream) {
    const float* feat   = (const float*)d_in[0];
    const float* weight = (const float*)d_in[1];
    const float* bias   = (const float*)d_in[2];
    const int*   src    = (const int*)d_in[3];

    const int OUT = in_sizes[2];            // 256
    const int IN  = in_sizes[1] / OUT;      // 512
    const int N   = in_sizes[0] / IN;       // 20000
    const int DEG = in_sizes[3] / N;        // 16
    (void)IN; (void)DEG; (void)out_size; (void)ws_size; (void)n_in;

    const float scale = 1.0f / sqrtf((float)DEG);

    // ws layout: h fp16 (N*256*2 B) | hnorm2 (N f32) | Wp (256 KB)
    char* ws = (char*)d_ws;
    __half* h     = (__half*)ws;
    float* hnorm2 = (float*)(ws + (size_t)N * NOUT * 2);
    unsigned int* Wp = (unsigned int*)(ws + (size_t)N * NOUT * 2 + (size_t)N * 4);

    float* out = (float*)d_out;

    const int nbm = (N + BM - 1) / BM;      // 625

    hipLaunchKernelGGL(prep_w_kernel, dim3(256), dim3(64), 0, stream,
                       weight, Wp);
    hipLaunchKernelGGL(gemm_mobius_kernel, dim3(nbm), dim3(256), 0, stream,
                       feat, (const uint4*)Wp, h, hnorm2, scale, N);
    hipLaunchKernelGGL(aggregate_kernel, dim3((N + 15) / 16), dim3(256), 0, stream,
                       h, hnorm2, src, bias, out, scale, N);
}